// Round 4
// baseline (192.843 us; speedup 1.0000x reference)
//
#include <hip/hip_runtime.h>

#define HDIM 128
#define WDIM 128
#define NPIX (HDIM * WDIM)   // 16384
#define NEDGE (2 * NPIX)     // 32768
#define BANDS 256            // value-buckets: bucket = 255 - floor(a*256)
#define MAXK 256             // per-band key capacity (cnt ~ N(128, 11))
#define NCP 7                // UF snapshots at band = 32*c, c = 1..7 (slot c-1)
#define CPSL 32              // cooperating slice-WGs per (img, checkpoint)
#define SENT 0xFFFFFFFFu     // global-UF root marker (memset(0xFF)-initializable)

typedef unsigned long long ull;

__device__ __forceinline__ void decode_edge(unsigned e, int& u, int& v) {
  if (e >= (unsigned)NEDGE) { u = 0; v = 0; return; }  // pad sentinel
  if (e < NPIX) {                       // vertical edge (i,j)-(i+1,j)
    if (e < NPIX - WDIM) { u = (int)e; v = (int)e + WDIM; } else { u = 0; v = 0; }
  } else {                              // horizontal edge (i,j)-(i,j+1)
    unsigned t2 = e - NPIX;
    if ((t2 & (WDIM - 1)) != (WDIM - 1)) { u = (int)t2; v = (int)t2 + 1; } else { u = 0; v = 0; }
  }
}

__device__ __forceinline__ int bucket_of(float a) {
  // a in [0,1). *256 is exact (pow2), floor monotone; equal floats -> same bucket.
  int f = (int)(a * 256.0f);
  f = f < 0 ? 0 : (f > 255 ? 255 : f);
  return 255 - f;                       // bucket 0 = highest affinity
}

// ---------------- global-memory UF (checkpoint builder) ----------------
// Roots hold SENT (so memset(0xFF) is init). Agent-scope loads/stores keep
// cross-XCD visibility; the hook CAS is device-scope (default). Stale plain
// reads are benign (validated by CAS); compression stores are hints.
__device__ __forceinline__ unsigned gld(const unsigned* p) {
  return __hip_atomic_load(p, __ATOMIC_RELAXED, __HIP_MEMORY_SCOPE_AGENT);
}
__device__ __forceinline__ void gst(unsigned* p, unsigned v) {
  __hip_atomic_store(p, v, __ATOMIC_RELAXED, __HIP_MEMORY_SCOPE_AGENT);
}
__device__ __forceinline__ int gfind(unsigned* p, int x) {
  while (true) {
    unsigned px = gld(&p[x]);
    if (px == SENT) return x;
    unsigned gp = gld(&p[(int)px]);
    if (gp == SENT) return (int)px;
    gst(&p[x], gp);                     // path-halving (benign race)
    x = (int)gp;
  }
}

// Grid: B * NCP * CPSL WGs; 1024 threads = 1 edge each (NEDGE/CPSL = 1024).
// WG (img, c, s) hooks its slice's edges with bucket < 32c into snapshot c.
__global__ __launch_bounds__(1024) void cp_kernel(const float* __restrict__ aff_g,
                                                  unsigned* __restrict__ parents) {
  const int bid = blockIdx.x;
  const int img = bid / (NCP * CPSL);
  const int r = bid % (NCP * CPSL);
  const int c = r / CPSL + 1;          // 1..7
  const int s = r % CPSL;
  const float* aff = aff_g + (size_t)img * NEDGE;
  unsigned* par = parents + ((size_t)img * NCP + (c - 1)) * NPIX;
  const int e = s * (NEDGE / CPSL) + threadIdx.x;
  const float a = aff[e];
  if (bucket_of(a) >= c * 32) return;
  int u, v; decode_edge((unsigned)e, u, v);
  if (u == v) return;                  // boundary self-edge
  while (true) {
    int ru = gfind(par, u), rv = gfind(par, v);
    if (ru == rv) return;
    if (ru < rv) { int t = ru; ru = rv; rv = t; }   // hook larger index under smaller
    unsigned old = atomicCAS(&par[ru], SENT, (unsigned)rv);
    if (old == SENT) return;
    u = ru; v = rv;
  }
}

// ---------------- band kernel helpers (LDS UF) ----------------
// Lock-free find with benign-race path compression (ECL-CC style).
__device__ __forceinline__ int cc_find(volatile unsigned* p, int x) {
  int px = (int)p[x];
  while (px != x) {
    int g = (int)p[px];
    if (g != px) p[x] = (unsigned)g;
    x = px; px = g;
  }
  return x;
}

// Interleaved path-halving find for two nodes (single-wave serial phase).
// pn[i] = (nz<<16)|parent for roots; plain parent for non-roots.
__device__ __forceinline__ void uf_find2(unsigned* pn, int x, int y,
                                         int& rx, int& ry,
                                         unsigned& nzx, unsigned& nzy) {
  unsigned wx = pn[x];
  unsigned wy = pn[y];
  while (true) {
    int px = (int)(wx & 0xFFFFu);
    int py = (int)(wy & 0xFFFFu);
    bool mx = (px != x);
    bool my = (py != y);
    if (!mx && !my) break;
    if (mx) {
      unsigned wpx = pn[px];
      int gx = (int)(wpx & 0xFFFFu);
      if (gx != px) { pn[x] = (wx & 0xFFFF0000u) | (unsigned)gx; x = gx; wx = pn[gx]; }
      else { x = px; wx = wpx; }
    }
    if (my) {
      unsigned wpy = pn[py];
      int gy = (int)(wpy & 0xFFFFu);
      if (gy != py) { pn[y] = (wy & 0xFFFF0000u) | (unsigned)gy; y = gy; wy = pn[gy]; }
      else { y = py; wy = wpy; }
    }
  }
  rx = x; ry = y; nzx = wx >> 16; nzy = wy >> 16;
}

// 64-bit shfl_xor built from two 32-bit ops (portable across HIP versions).
__device__ __forceinline__ ull shflx64(ull x, int m) {
  int lo = __shfl_xor((int)(unsigned)x, m, 64);
  int hi = __shfl_xor((int)(unsigned)(x >> 32), m, 64);
  return ((ull)(unsigned)hi << 32) | (unsigned)lo;
}

// One WG per (image, band). UF seeded from snapshot band>>5; intra-range CC
// only over buckets [32*(band>>5), band) -- ~8x less CC work than full prefix.
__global__ __launch_bounds__(1024) void band_kernel(const int* __restrict__ gt,
                                                    const float* __restrict__ aff_g,
                                                    const unsigned* __restrict__ parents,
                                                    float* __restrict__ out) {
  __shared__ unsigned pn[NPIX];   // 64 KiB union-find (reused as histogram for band 0)
  __shared__ ull skbuf[MAXK];     // 2 KiB band-edge keys
  __shared__ unsigned scnt;
  const int img = blockIdx.x / BANDS;
  const int braw = blockIdx.x % BANDS;
  const int band = (img & 1) ? (BANDS - 1 - braw) : braw;   // load-balance swizzle
  const int* lab = gt + (size_t)img * NPIX;
  const float* aff = aff_g + (size_t)img * NEDGE;
  const int tid = threadIdx.x;

  // Band 0 additionally contributes +0.5 * P_same (label histogram term).
  if (band == 0) {
    if (tid < 64) pn[tid] = 0;
    __syncthreads();
    for (int i = tid; i < NPIX; i += 1024) atomicAdd(&pn[(unsigned)lab[i] & 63u], 1u);
    __syncthreads();
    if (tid == 0) {
      double s = 0.0;
      for (int l = 1; l < 64; ++l) { double m = (double)pn[l]; s += m * (m - 1.0) * 0.5; }
      atomicAdd(out, (float)(0.5 * s));
    }
    __syncthreads();
  }

  // ---- seed UF: identity (bands < 32) or checkpoint snapshot ----
  const int cbase = band & ~31;        // 32 * (band >> 5)
  if (cbase == 0) {
    for (int i = tid; i < NPIX / 4; i += 1024) {
      uint4 w; w.x = 4u * i; w.y = 4u * i + 1u; w.z = 4u * i + 2u; w.w = 4u * i + 3u;
      ((uint4*)pn)[i] = w;
    }
  } else {
    const unsigned* par = parents + ((size_t)img * NCP + (band >> 5) - 1) * NPIX;
    for (int i = tid; i < NPIX / 4; i += 1024) {
      uint4 w = ((const uint4*)par)[i];
      const unsigned b0 = 4u * (unsigned)i;
      w.x = (w.x == SENT) ? b0 : w.x;
      w.y = (w.y == SENT) ? b0 + 1u : w.y;
      w.z = (w.z == SENT) ? b0 + 2u : w.z;
      w.w = (w.w == SENT) ? b0 + 3u : w.w;
      ((uint4*)pn)[i] = w;
    }
  }
  if (tid == 0) scnt = 0;
  __syncthreads();

  // ---- fused scan: CC over buckets [cbase, band) + collect bucket==band keys ----
  volatile unsigned* vp = pn;
  const float4* aff4 = (const float4*)aff;
  for (int t4 = tid; t4 < NEDGE / 4; t4 += 1024) {     // 8 iterations, 16B/lane
    const float4 q = aff4[t4];
#pragma unroll
    for (int s = 0; s < 4; ++s) {
      const float a = (s == 0) ? q.x : (s == 1) ? q.y : (s == 2) ? q.z : q.w;
      const int b = bucket_of(a);
      if (b > band || b < cbase) continue;             // snapshot covers b < cbase
      const unsigned e = (unsigned)(t4 * 4 + s);
      int u, v; decode_edge(e, u, v);
      if (u == v) continue;             // boundary self-edges: provable no-ops
      if (b == band) {
        unsigned bits = __float_as_uint(a);
        unsigned ob = (bits & 0x80000000u) ? ~bits : (bits | 0x80000000u);
        unsigned pos = atomicAdd(&scnt, 1u);
        if (pos < MAXK) skbuf[pos] = ((ull)(~ob) << 32) | e;  // asc key == desc aff
      } else {
        while (true) {
          int ru = cc_find(vp, u), rv = cc_find(vp, v);
          if (ru == rv) break;
          if (ru < rv) { int t = ru; ru = rv; rv = t; }  // hook larger under smaller
          unsigned old = atomicCAS(&pn[ru], (unsigned)ru, (unsigned)rv);
          if (old == (unsigned)ru) break;
          u = ru; v = rv;
        }
      }
    }
  }
  __syncthreads();
  unsigned cnt = scnt; if (cnt > MAXK) cnt = MAXK;

  // ---- wave 0: register bitonic sort (256 keys, 4/lane, idx = r*64+lane).
  //      waves 1..15: flatten + masses (runs concurrently; no barriers inside).
  ull myv[4];
  if (tid < 64) {
    const int lane = tid;
#pragma unroll
    for (int r = 0; r < 4; ++r) {
      unsigned idx = (unsigned)(r * 64 + lane);
      myv[r] = (idx < cnt) ? skbuf[idx] : ~0ull;
    }
    // Bitonic network over idx in [0,256); idx = r*64 + lane.
    // j>=64: partner is register r^(j>>6) in-lane. j<64: partner lane^j via shfl.
#pragma unroll
    for (unsigned k = 2; k <= 256; k <<= 1) {
#pragma unroll
      for (unsigned j = k >> 1; j; j >>= 1) {
        if (j >= 64) {
          const int rj = (int)(j >> 6);
#pragma unroll
          for (int r = 0; r < 4; ++r) {
            if (!(r & rj)) {
              const int p = r | rj;
              const bool dir = ((((unsigned)r << 6) & k) == 0);  // ascending block?
              ull a0 = myv[r], a1 = myv[p];
              if ((a0 > a1) == dir) { myv[r] = a1; myv[p] = a0; }
            }
          }
        } else {
#pragma unroll
          for (int r = 0; r < 4; ++r) {
            ull pv = shflx64(myv[r], (int)j);
            const bool low = ((lane & (int)j) == 0);
            const bool dir = (((((unsigned)r << 6) | (unsigned)lane) & k) == 0);
            const bool takemin = (low == dir);
            const bool less = (myv[r] < pv);
            myv[r] = (less == takemin) ? myv[r] : pv;
          }
        }
      }
    }
  } else {
    // Flatten + masses via stride-960 RLE: lane-consecutive addresses are
    // conflict-free; RLE + wave fast-path keeps same-address atomics bounded.
    const int t = tid - 64;
    int prev = -1; unsigned acc = 0; bool multi = false;
    for (int k = 0; k < 18; ++k) {
      int i = t + k * 960;
      if (i >= NPIX) break;
      int r = i; unsigned p;
      while (((p = vp[r]) & 0xFFFFu) != (unsigned)r) r = (int)(p & 0xFFFFu);
      if (i != r) pn[i] = (unsigned)r;        // non-roots: plain root index
      unsigned c = (lab[i] != 0) ? 1u : 0u;
      if (r != prev) {
        if (prev >= 0) { if (acc) atomicAdd(&pn[prev], acc << 16); multi = true; }
        prev = r; acc = c;
      } else {
        acc += c;
      }
    }
    // Wave fast-path: one giant component (late bands) -> 1 atomic per wave.
    const int wl = tid & 63;
    int first = __shfl(prev, 0);
    bool uni = __all(!multi && prev == first);
    if (uni) {
      unsigned s = acc;
      for (int off = 32; off; off >>= 1) s += __shfl_down(s, off);
      if (wl == 0 && s) atomicAdd(&pn[prev], s << 16);
    } else if (acc) {
      atomicAdd(&pn[prev], acc << 16);        // roots: (nz<<16)|r
    }
  }
  __syncthreads();

  // ---- serial Kruskal over this band's cnt edges (sorted, in wave-0 regs) ----
  if (tid < 64) {
    const int lane = tid;
    double acc = 0.0;
#pragma unroll
    for (int b8 = 0; b8 < 4; ++b8) {
      if ((unsigned)(b8 * 64) >= cnt) break;
      const ull myk_b = myv[b8];              // sorted position b8*64 + lane
      unsigned e = (unsigned)myk_b;
      unsigned khi = (unsigned)(myk_b >> 32);
      int u, v; decode_edge(e, u, v);         // pad keys -> u==v -> invalid
      const bool valid = (u != v);
      unsigned ob = ~khi;
      unsigned bits = (ob & 0x80000000u) ? (ob & 0x7FFFFFFFu) : ~ob;
      const float a = __uint_as_float(bits);

      // parallel pre-find (trees are flat: depth ~1)
      int ru, rv; unsigned nzu, nzv;
      uf_find2(pn, u, v, ru, rv, nzu, nzv);

      // branchless serial resolution over active lanes
      unsigned long long m = __ballot(valid && (ru != rv));
      int myW = 0, myL = 0; unsigned snap = 0;
      while (m) {
        const int j = (int)(__ffsll(m) - 1);
        m &= m - 1;
        const int ruj = __builtin_amdgcn_readlane(ru, j);
        const int rvj = __builtin_amdgcn_readlane(rv, j);
        const unsigned nzuj = (unsigned)__builtin_amdgcn_readlane((int)nzu, j);
        const unsigned nzvj = (unsigned)__builtin_amdgcn_readlane((int)nzv, j);
        const bool live = (ruj != rvj);
        const unsigned mnz = nzuj + nzvj;
        int W = (nzuj >= nzvj) ? ruj : rvj;
        int L = ruj + rvj - W;
        W = live ? W : -1;                 // sentinels make updates no-ops
        L = live ? L : -1;
        const int sj = live ? j : 64;
        const unsigned spk = nzuj | (nzvj << 16);
        const bool turn = (lane == sj);
        if (turn) { myW = W; myL = L; snap = spk; }
        const bool uW = (ru == W), uL = (ru == L);
        const bool vW = (rv == W), vL = (rv == L);
        if (uL) ru = W;
        if (uW | uL) nzu = mnz;
        if (vL) rv = W;
        if (vW | vL) nzv = mnz;
      }
      // writeback (wave-ordered LDS; only roots carry nz bits)
      pn[u] = (unsigned)ru;
      pn[v] = (unsigned)rv;
      if (myW != myL) {
        pn[myL] = (unsigned)myW;
        acc += (double)((snap & 0xFFFFu) * (snap >> 16)) * (double)a;
      }
      pn[ru] = (nzu << 16) | (unsigned)ru;
      pn[rv] = (nzv << 16) | (unsigned)rv;
    }
    for (int off = 32; off > 0; off >>= 1) acc += __shfl_down(acc, off);
    if (lane == 0) atomicAdd(out, (float)(-0.5 * acc));
  }
}

extern "C" void kernel_launch(void* const* d_in, const int* in_sizes, int n_in,
                              void* d_out, int out_size, void* d_ws, size_t ws_size,
                              hipStream_t stream) {
  const float* aff = (const float*)d_in[0];
  const int* gt = (const int*)d_in[1];
  float* out = (float*)d_out;
  const int B = in_sizes[1] / NPIX;  // 2 images
  unsigned* parents = (unsigned*)d_ws;   // B * NCP * NPIX u32 = 896 KiB for B=2

  hipMemsetAsync(d_out, 0, sizeof(float) * (size_t)out_size, stream);
  hipMemsetAsync(d_ws, 0xFF, (size_t)B * NCP * NPIX * sizeof(unsigned), stream);
  cp_kernel<<<dim3(B * NCP * CPSL), dim3(1024), 0, stream>>>(aff, parents);
  band_kernel<<<dim3(B * BANDS), dim3(1024), 0, stream>>>(gt, aff, parents, out);
}

// Round 5
// 144.046 us; speedup vs baseline: 1.3388x; 1.3388x over previous
//
#include <hip/hip_runtime.h>

#define HDIM 128
#define WDIM 128
#define NPIX (HDIM * WDIM)   // 16384
#define NEDGE (2 * NPIX)     // 32768
#define BANDS 256            // value-buckets: bucket = 255 - floor(a*256)
#define MAXK 256             // per-band key capacity (cnt ~ N(128, 11))
#define NCID 512             // compact-root capacity (<= 2*MAXK)
#define HTSZ 1024            // endpoint-root hash table (load <= 0.5)

typedef unsigned long long ull;

__device__ __forceinline__ void decode_edge(unsigned e, int& u, int& v) {
  if (e >= (unsigned)NEDGE) { u = 0; v = 0; return; }  // pad sentinel
  if (e < NPIX) {                       // vertical edge (i,j)-(i+1,j)
    if (e < NPIX - WDIM) { u = (int)e; v = (int)e + WDIM; } else { u = 0; v = 0; }
  } else {                              // horizontal edge (i,j)-(i,j+1)
    unsigned t2 = e - NPIX;
    if ((t2 & (WDIM - 1)) != (WDIM - 1)) { u = (int)t2; v = (int)t2 + 1; } else { u = 0; v = 0; }
  }
}

__device__ __forceinline__ int bucket_of(float a) {
  // a in [0,1). *256 is exact (pow2), floor monotone; equal floats -> same bucket.
  int f = (int)(a * 256.0f);
  f = f < 0 ? 0 : (f > 255 ? 255 : f);
  return 255 - f;                       // bucket 0 = highest affinity
}

// Lock-free find with benign-race path compression (ECL-CC style).
__device__ __forceinline__ int cc_find(volatile unsigned* p, int x) {
  int px = (int)p[x];
  while (px != x) {
    int g = (int)p[px];
    if (g != px) p[x] = (unsigned)g;
    x = px; px = g;
  }
  return x;
}

// Interleaved path-halving find for two nodes (single-wave serial phase).
// pn[i] = (nz<<16)|parent for roots; plain parent for non-roots.
__device__ __forceinline__ void uf_find2(unsigned* pn, int x, int y,
                                         int& rx, int& ry,
                                         unsigned& nzx, unsigned& nzy) {
  unsigned wx = pn[x];
  unsigned wy = pn[y];
  while (true) {
    int px = (int)(wx & 0xFFFFu);
    int py = (int)(wy & 0xFFFFu);
    bool mx = (px != x);
    bool my = (py != y);
    if (!mx && !my) break;
    if (mx) {
      unsigned wpx = pn[px];
      int gx = (int)(wpx & 0xFFFFu);
      if (gx != px) { pn[x] = (wx & 0xFFFF0000u) | (unsigned)gx; x = gx; wx = pn[gx]; }
      else { x = px; wx = wpx; }
    }
    if (my) {
      unsigned wpy = pn[py];
      int gy = (int)(wpy & 0xFFFFu);
      if (gy != py) { pn[y] = (wy & 0xFFFF0000u) | (unsigned)gy; y = gy; wy = pn[gy]; }
      else { y = py; wy = wpy; }
    }
  }
  rx = x; ry = y; nzx = wx >> 16; nzy = wy >> 16;
}

// 64-bit shfl_xor built from two 32-bit ops (portable across HIP versions).
__device__ __forceinline__ ull shflx64(ull x, int m) {
  int lo = __shfl_xor((int)(unsigned)x, m, 64);
  int hi = __shfl_xor((int)(unsigned)(x >> 32), m, 64);
  return ((ull)(unsigned)hi << 32) | (unsigned)lo;
}

// root -> compact id via LDS hash (insert-or-lookup). Entry = (root+1)<<16 | cid.
__device__ __forceinline__ unsigned cid_of(unsigned root, unsigned* htab, unsigned* hcnt) {
  unsigned h = (root * 2654435761u) >> 22;      // top bits -> [0, 1024)
  const unsigned tag = (root + 1u) << 16;       // root+1 <= 16384, fits 16 bits
  while (true) {
    unsigned cur = htab[h & (HTSZ - 1)];
    if (cur == 0u) {
      unsigned cid = atomicAdd(hcnt, 1u);       // attempts <= 2*MAXK = NCID
      unsigned old = atomicCAS(&htab[h & (HTSZ - 1)], 0u, tag | cid);
      if (old == 0u) return cid;
      cur = old;                                // lost race; re-examine
    }
    if ((cur & 0xFFFF0000u) == tag) return cur & 0xFFFFu;
    ++h;
  }
}

// Phase A: per (img, band) WG -- prefix CC + flatten + masses + compact-emit.
// Emits: sorted-ready keys (affbits | e | slot), cid pairs, per-cid masses, cnt.
__global__ __launch_bounds__(1024) void band_a(const int* __restrict__ gt,
                                               const float* __restrict__ aff_g,
                                               ull* __restrict__ keys_g,
                                               unsigned* __restrict__ cids_g,
                                               unsigned* __restrict__ nzt_g,
                                               unsigned* __restrict__ cnt_g,
                                               float* __restrict__ out) {
  __shared__ unsigned pn[NPIX];   // 64 KiB union-find (reused as histogram for band 0)
  __shared__ ull skbuf[MAXK];     // 2 KiB band-edge keys (collect order)
  __shared__ unsigned htab[HTSZ]; // 4 KiB root->cid hash
  __shared__ unsigned nzt[NCID];  // 2 KiB per-cid nonzero-mass
  __shared__ unsigned scnt, ccnt;
  const int img = blockIdx.x / BANDS;
  const int braw = blockIdx.x % BANDS;
  const int band = (img & 1) ? (BANDS - 1 - braw) : braw;   // load-balance swizzle
  const int* lab = gt + (size_t)img * NPIX;
  const float* aff = aff_g + (size_t)img * NEDGE;
  const int tid = threadIdx.x;

  if (tid < HTSZ) htab[tid] = 0u;
  if (tid < NCID) nzt[tid] = 0u;
  if (tid == 0) { scnt = 0u; ccnt = 0u; }

  // Band 0 additionally contributes +0.5 * P_same (label histogram term).
  if (band == 0) {
    if (tid < 64) pn[tid] = 0;
    __syncthreads();
    for (int i = tid; i < NPIX; i += 1024) atomicAdd(&pn[(unsigned)lab[i] & 63u], 1u);
    __syncthreads();
    if (tid == 0) {
      double s = 0.0;
      for (int l = 1; l < 64; ++l) { double m = (double)pn[l]; s += m * (m - 1.0) * 0.5; }
      atomicAdd(out, (float)(0.5 * s));
    }
    __syncthreads();
  }

  // ---- init UF (vectorized identity) ----
  for (int i = tid; i < NPIX / 4; i += 1024) {
    uint4 w; w.x = 4u * i; w.y = 4u * i + 1u; w.z = 4u * i + 2u; w.w = 4u * i + 3u;
    ((uint4*)pn)[i] = w;
  }
  __syncthreads();

  // ---- fused scan: CC over bucket<band edges + collect bucket==band keys ----
  volatile unsigned* vp = pn;
  const float4* aff4 = (const float4*)aff;
  for (int t4 = tid; t4 < NEDGE / 4; t4 += 1024) {     // 8 iterations, 16B/lane
    const float4 q = aff4[t4];
#pragma unroll
    for (int s = 0; s < 4; ++s) {
      const float a = (s == 0) ? q.x : (s == 1) ? q.y : (s == 2) ? q.z : q.w;
      const int b = bucket_of(a);
      if (b > band) continue;
      const unsigned e = (unsigned)(t4 * 4 + s);
      int u, v; decode_edge(e, u, v);
      if (u == v) continue;             // boundary self-edges: provable no-ops
      if (b == band) {
        unsigned bits = __float_as_uint(a);
        unsigned ob = (bits & 0x80000000u) ? ~bits : (bits | 0x80000000u);
        unsigned pos = atomicAdd(&scnt, 1u);
        if (pos < MAXK) skbuf[pos] = ((ull)(~ob) << 32) | e;  // asc key == desc aff
      } else {
        while (true) {
          int ru = cc_find(vp, u), rv = cc_find(vp, v);
          if (ru == rv) break;
          if (ru < rv) { int t = ru; ru = rv; rv = t; }  // hook larger under smaller
          unsigned old = atomicCAS(&pn[ru], (unsigned)ru, (unsigned)rv);
          if (old == (unsigned)ru) break;
          u = ru; v = rv;
        }
      }
    }
  }
  __syncthreads();
  unsigned cnt = scnt; if (cnt > MAXK) cnt = MAXK;

  // ---- flatten + masses (waves 1..15; stride-960 RLE + wave fast-path) ----
  if (tid >= 64) {
    const int t = tid - 64;
    int prev = -1; unsigned acc = 0; bool multi = false;
    for (int k = 0; k < 18; ++k) {
      int i = t + k * 960;
      if (i >= NPIX) break;
      int r = i; unsigned p;
      while (((p = vp[r]) & 0xFFFFu) != (unsigned)r) r = (int)(p & 0xFFFFu);
      if (i != r) pn[i] = (unsigned)r;        // non-roots: plain root index
      unsigned c = (lab[i] != 0) ? 1u : 0u;
      if (r != prev) {
        if (prev >= 0) { if (acc) atomicAdd(&pn[prev], acc << 16); multi = true; }
        prev = r; acc = c;
      } else {
        acc += c;
      }
    }
    const int wl = tid & 63;
    int first = __shfl(prev, 0);
    bool uni = __all(!multi && prev == first);
    if (uni) {
      unsigned s = acc;
      for (int off = 32; off; off >>= 1) s += __shfl_down(s, off);
      if (wl == 0 && s) atomicAdd(&pn[prev], s << 16);
    } else if (acc) {
      atomicAdd(&pn[prev], acc << 16);        // roots: (nz<<16)|r
    }
  }
  __syncthreads();

  // ---- compact-emit: dedup endpoint roots -> cids; dump keys/cids/masses ----
  if (tid < (int)cnt) {
    const ull key = skbuf[tid];
    const unsigned e = (unsigned)key;
    int u, v; decode_edge(e, u, v);
    const unsigned ru = pn[u] & 0xFFFFu;      // post-flatten: one step to root
    const unsigned rv = pn[v] & 0xFFFFu;
    const unsigned cu = cid_of(ru, htab, &ccnt);
    const unsigned cv = cid_of(rv, htab, &ccnt);
    nzt[cu] = pn[ru] >> 16;                   // dup writes carry same value
    nzt[cv] = pn[rv] >> 16;
    keys_g[(size_t)blockIdx.x * MAXK + tid] =
        (key & 0xFFFFFFFF00000000ull) | ((ull)(e << 16)) | (unsigned)tid;
    cids_g[(size_t)blockIdx.x * MAXK + tid] = (cu << 16) | cv;
  }
  __syncthreads();
  if (tid < NCID) nzt_g[(size_t)blockIdx.x * NCID + tid] = nzt[tid];
  if (tid == 0) cnt_g[blockIdx.x] = cnt;
}

// Phase B: one wave per band. Register bitonic sort + serial Kruskal on the
// compact (<=512 node) UF. Bijective root relabel => identical arithmetic.
__global__ __launch_bounds__(64) void band_b(const ull* __restrict__ keys_g,
                                             const unsigned* __restrict__ cids_g,
                                             const unsigned* __restrict__ nzt_g,
                                             const unsigned* __restrict__ cnt_g,
                                             float* __restrict__ out) {
  __shared__ unsigned pn2[NCID];  // 2 KiB compact UF: (nz<<16)|parent
  __shared__ unsigned cid2[MAXK]; // 1 KiB slot -> cid pair
  const int bid = blockIdx.x;
  const int lane = threadIdx.x;
  const unsigned cnt = cnt_g[bid];

#pragma unroll
  for (int r = 0; r < NCID / 64; ++r) {       // 8
    const int i = r * 64 + lane;
    pn2[i] = (nzt_g[(size_t)bid * NCID + i] << 16) | (unsigned)i;
  }
#pragma unroll
  for (int r = 0; r < MAXK / 64; ++r) {       // 4
    const int j = r * 64 + lane;
    cid2[j] = cids_g[(size_t)bid * MAXK + j];
  }
  ull myv[4];
#pragma unroll
  for (int r = 0; r < 4; ++r) {
    const unsigned idx = (unsigned)(r * 64 + lane);
    myv[r] = (idx < cnt) ? keys_g[(size_t)bid * MAXK + idx] : ~0ull;
  }
  __syncthreads();

  // Bitonic network over idx in [0,256); idx = r*64 + lane.
#pragma unroll
  for (unsigned k = 2; k <= 256; k <<= 1) {
#pragma unroll
    for (unsigned j = k >> 1; j; j >>= 1) {
      if (j >= 64) {
        const int rj = (int)(j >> 6);
#pragma unroll
        for (int r = 0; r < 4; ++r) {
          if (!(r & rj)) {
            const int p = r | rj;
            const bool dir = ((((unsigned)r << 6) & k) == 0);  // ascending block?
            ull a0 = myv[r], a1 = myv[p];
            if ((a0 > a1) == dir) { myv[r] = a1; myv[p] = a0; }
          }
        }
      } else {
#pragma unroll
        for (int r = 0; r < 4; ++r) {
          ull pv = shflx64(myv[r], (int)j);
          const bool low = ((lane & (int)j) == 0);
          const bool dir = (((((unsigned)r << 6) | (unsigned)lane) & k) == 0);
          const bool takemin = (low == dir);
          const bool less = (myv[r] < pv);
          myv[r] = (less == takemin) ? myv[r] : pv;
        }
      }
    }
  }

  // prefetch cid pairs for sorted slots (pad -> clamp to 0; masked by valid)
  unsigned cp_[4];
#pragma unroll
  for (int r = 0; r < 4; ++r) {
    const unsigned pos = (unsigned)myv[r] & 0xFFu;
    cp_[r] = (myv[r] != ~0ull) ? cid2[pos] : 0u;
  }

  // ---- serial Kruskal over cnt edges (sorted, in regs; compact UF) ----
  double acc = 0.0;
#pragma unroll
  for (int b8 = 0; b8 < 4; ++b8) {
    if ((unsigned)(b8 * 64) >= cnt) break;
    const ull myk_b = myv[b8];
    const bool valid = (myk_b != ~0ull);
    const int u = (int)(cp_[b8] >> 16);
    const int v = (int)(cp_[b8] & 0xFFFFu);
    const unsigned khi = (unsigned)(myk_b >> 32);
    const unsigned ob = ~khi;
    const unsigned bits = (ob & 0x80000000u) ? (ob & 0x7FFFFFFFu) : ~ob;
    const float a = __uint_as_float(bits);

    // parallel pre-find (trees are flat: depth ~1)
    int ru, rv; unsigned nzu, nzv;
    uf_find2(pn2, u, v, ru, rv, nzu, nzv);

    // branchless serial resolution over active lanes
    unsigned long long m = __ballot(valid && (ru != rv));
    int myW = 0, myL = 0; unsigned snap = 0;
    while (m) {
      const int j = (int)(__ffsll(m) - 1);
      m &= m - 1;
      const int ruj = __builtin_amdgcn_readlane(ru, j);
      const int rvj = __builtin_amdgcn_readlane(rv, j);
      const unsigned nzuj = (unsigned)__builtin_amdgcn_readlane((int)nzu, j);
      const unsigned nzvj = (unsigned)__builtin_amdgcn_readlane((int)nzv, j);
      const bool live = (ruj != rvj);
      const unsigned mnz = nzuj + nzvj;
      int W = (nzuj >= nzvj) ? ruj : rvj;
      int L = ruj + rvj - W;
      W = live ? W : -1;                 // sentinels make updates no-ops
      L = live ? L : -1;
      const int sj = live ? j : 64;
      const unsigned spk = nzuj | (nzvj << 16);
      const bool turn = (lane == sj);
      if (turn) { myW = W; myL = L; snap = spk; }
      const bool uW = (ru == W), uL = (ru == L);
      const bool vW = (rv == W), vL = (rv == L);
      if (uL) ru = W;
      if (uW | uL) nzu = mnz;
      if (vL) rv = W;
      if (vW | vL) nzv = mnz;
    }
    // writeback (wave-ordered LDS; only roots carry nz bits)
    pn2[u] = (unsigned)ru;
    pn2[v] = (unsigned)rv;
    if (myW != myL) {
      pn2[myL] = (unsigned)myW;
      acc += (double)((snap & 0xFFFFu) * (snap >> 16)) * (double)a;
    }
    pn2[ru] = (nzu << 16) | (unsigned)ru;
    pn2[rv] = (nzv << 16) | (unsigned)rv;
  }
  for (int off = 32; off > 0; off >>= 1) acc += __shfl_down(acc, off);
  if (lane == 0) atomicAdd(out, (float)(-0.5 * acc));
}

extern "C" void kernel_launch(void* const* d_in, const int* in_sizes, int n_in,
                              void* d_out, int out_size, void* d_ws, size_t ws_size,
                              hipStream_t stream) {
  const float* aff = (const float*)d_in[0];
  const int* gt = (const int*)d_in[1];
  float* out = (float*)d_out;
  const int B = in_sizes[1] / NPIX;  // 2 images
  const int NWG = B * BANDS;         // 512

  ull* keys = (ull*)d_ws;                                  // NWG*MAXK ull  = 1 MB
  unsigned* cids = (unsigned*)(keys + (size_t)NWG * MAXK); // NWG*MAXK u32  = 512 KB
  unsigned* nzt = cids + (size_t)NWG * MAXK;               // NWG*NCID u32  = 1 MB
  unsigned* cntg = nzt + (size_t)NWG * NCID;               // NWG u32

  hipMemsetAsync(d_out, 0, sizeof(float) * (size_t)out_size, stream);
  band_a<<<dim3(NWG), dim3(1024), 0, stream>>>(gt, aff, keys, cids, nzt, cntg, out);
  band_b<<<dim3(NWG), dim3(64), 0, stream>>>(keys, cids, nzt, cntg, out);
}